// Round 4
// baseline (325.355 us; speedup 1.0000x reference)
//
#include <hip/hip_runtime.h>
#include <hip/hip_bf16.h>

typedef float v4f __attribute__((ext_vector_type(4)));
typedef short v8s __attribute__((ext_vector_type(8)));
typedef unsigned short u16x8 __attribute__((ext_vector_type(8)));

// ---------- helpers ----------
__device__ __forceinline__ float bf2f(ushort u) {
    union { unsigned int i; float f; } v; v.i = ((unsigned int)u) << 16; return v.f;
}
__device__ __forceinline__ ushort f2bf(float f) {
    union { float f; unsigned int i; } v; v.f = f;
    unsigned int x = v.i;
    unsigned int r = (x + 0x7fffu + ((x >> 16) & 1u)) >> 16;   // RNE
    return (ushort)r;
}
__device__ __forceinline__ void gld_lds16(const ushort* g, ushort* l) {
    __builtin_amdgcn_global_load_lds(
        (const __attribute__((address_space(1))) unsigned int*)g,
        (__attribute__((address_space(3))) unsigned int*)l, 16, 0, 0);
}

// ---------- small utility kernels ----------
__global__ void zero_i32(int* p, int n) {
    int i = blockIdx.x * blockDim.x + threadIdx.x;
    if (i < n) p[i] = 0;
}

// x [M][128] fp32 -> dst [M][stride] bf16 (cols 0..127)
__global__ void cvt_strided(const float4* __restrict__ x, ushort* __restrict__ dst,
                            int total, int stride) {
    int idx = blockIdx.x * blockDim.x + threadIdx.x;
    if (idx >= total) return;
    int row = idx >> 5, c4 = idx & 31;
    float4 f = x[idx];
    ushort4 o;
    o.x = f2bf(f.x); o.y = f2bf(f.y); o.z = f2bf(f.z); o.w = f2bf(f.w);
    *reinterpret_cast<ushort4*>(dst + (size_t)row * stride + c4 * 4) = o;
}

// transpose(+concat) weights to bf16 [NC][Kt]:  dst[n][k] = k<K1 ? Wa[k][n] : Wb[k-K1][n]
__global__ void prep_wt(const float* __restrict__ Wa, const float* __restrict__ Wb,
                        ushort* __restrict__ dst, int K1, int Kt, int NC) {
    int idx = blockIdx.x * blockDim.x + threadIdx.x;
    if (idx >= Kt * NC) return;
    int n = idx / Kt, k = idx - n * Kt;
    float v = (k < K1) ? Wa[(size_t)k * NC + n] : Wb[(size_t)(k - K1) * NC + n];
    dst[idx] = f2bf(v);
}

__global__ void deg_kernel(const int* __restrict__ dst, int* __restrict__ deg, int E) {
    int e = blockIdx.x * blockDim.x + threadIdx.x;
    if (e < E) atomicAdd(&deg[dst[e]], 1);
}

__global__ void scan1(const int* __restrict__ deg, int* __restrict__ excl,
                      int* __restrict__ bsum, int N) {
    __shared__ int s[256];
    int tid = threadIdx.x;
    int gid = blockIdx.x * 256 + tid;
    int v = (gid < N) ? deg[gid] : 0;
    s[tid] = v;
    __syncthreads();
    for (int off = 1; off < 256; off <<= 1) {
        int t = (tid >= off) ? s[tid - off] : 0;
        __syncthreads();
        s[tid] += t;
        __syncthreads();
    }
    if (gid < N) excl[gid] = s[tid] - v;
    if (tid == 255) bsum[blockIdx.x] = s[255];
}

__global__ void scan2(int* __restrict__ bsum, int nb) {
    __shared__ int s[512];
    int tid = threadIdx.x;
    int v = (tid < nb) ? bsum[tid] : 0;
    s[tid] = v;
    __syncthreads();
    for (int off = 1; off < 512; off <<= 1) {
        int t = (tid >= off) ? s[tid - off] : 0;
        __syncthreads();
        s[tid] += t;
        __syncthreads();
    }
    if (tid < nb) bsum[tid] = s[tid] - v;
}

__global__ void add_off(int* __restrict__ offs, const int* __restrict__ bsum,
                        int* __restrict__ cursor, int N, int E) {
    int gid = blockIdx.x * blockDim.x + threadIdx.x;
    if (gid < N) {
        int o = offs[gid] + bsum[gid >> 8];
        offs[gid] = o;
        cursor[gid] = o;
    } else if (gid == N) {
        offs[N] = E;
    }
}

__global__ void fill_csr(const int* __restrict__ src, const int* __restrict__ dst,
                         int* __restrict__ cursor, int* __restrict__ csr, int E) {
    int e = blockIdx.x * blockDim.x + threadIdx.x;
    if (e < E) {
        int p = atomicAdd(&cursor[dst[e]], 1);
        csr[p] = src[e];
    }
}

// ---------- mean aggregation ----------
// One wave per node, 4 waves per block. Each lane loads 16B (ushort8);
// G = lanes per row (D*2/16); P = D/(8) ... P = 64/G = neighbors per VMEM instr.
// Sub-group g = lane/G processes neighbors i+g; butterfly-combine at the end.
template <int D>
__global__ void agg_mean(const ushort* __restrict__ h, int hs,
                         const int* __restrict__ off, const int* __restrict__ csr,
                         ushort* __restrict__ out, int os) {
    constexpr int G = D / 8;        // lanes covering one row (16B each): 16 or 32
    constexpr int P = 64 / G;       // parallel neighbors per wave: 4 or 2
    const int wid = threadIdx.x >> 6;
    const int n = blockIdx.x * 4 + wid;
    const int lane = threadIdx.x & 63;
    const int g = lane / G;         // neighbor sub-group
    const int sl = lane % G;        // 16B slot within row

    int s = off[n], e = off[n + 1];
    float acc[8];
#pragma unroll
    for (int k = 0; k < 8; ++k) acc[k] = 0.f;

    const ushort* hp = h + (size_t)sl * 8;

    auto accum = [&](int u) {
        u16x8 q = *reinterpret_cast<const u16x8*>(hp + (size_t)u * hs);
#pragma unroll
        for (int k = 0; k < 8; ++k) acc[k] += bf2f(q[k]);
    };

    int i = s;
    for (; i + 2 * P <= e; i += 2 * P) {   // 2-deep unroll: 2P rows in flight/wave
        int u0 = csr[i + g];
        int u1 = csr[i + P + g];
        u16x8 q0 = *reinterpret_cast<const u16x8*>(hp + (size_t)u0 * hs);
        u16x8 q1 = *reinterpret_cast<const u16x8*>(hp + (size_t)u1 * hs);
#pragma unroll
        for (int k = 0; k < 8; ++k) acc[k] += bf2f(q0[k]) + bf2f(q1[k]);
    }
    if (i + P <= e) {
        accum(csr[i + g]);
        i += P;
    }
    int r = e - i;                          // 0..P-1 remainder
    if (g < r) accum(csr[i + g]);

    // butterfly: sum across sub-groups (stride G, 2*G, ... up to 32)
#pragma unroll
    for (int m = G; m < 64; m <<= 1)
#pragma unroll
        for (int k = 0; k < 8; ++k) acc[k] += __shfl_xor(acc[k], m, 64);

    float inv = (e > s) ? 1.0f / (float)(e - s) : 1.0f;
    if (g == 0) {
        u16x8 o;
#pragma unroll
        for (int k = 0; k < 8; ++k) o[k] = f2bf(acc[k] * inv);
        *reinterpret_cast<u16x8*>(out + (size_t)n * os + sl * 8) = o;
    }
}

// ---------- MFMA GEMM (full-width tile, 2-phase double-buffered) ----------
// out = act( A @ Wt^T + bias ).  A: bf16 [M_pad][K] rs=K.  Wt: bf16 [BN][K].
// BM=128 x BN (==NC), BK=32, 512 threads = 8 waves (2m x 4n), per-wave 64 x BN/4.
// ACT: 0 = none->fp32, 1 = relu->bf16, 2 = BN+relu->bf16.  OS = out row stride.
template <int K, int BN, int ACT>
__launch_bounds__(512)
__global__ void gemm_mfma(const ushort* __restrict__ A, const ushort* __restrict__ Wt,
                          const float* __restrict__ bias, const float* __restrict__ gamma,
                          const float* __restrict__ beta,
                          ushort* __restrict__ outb, float* __restrict__ outf,
                          int M, int OS) {
    constexpr int BM = 128, BK = 32;
    constexpr int NJ = BN / 64;          // col frags per wave
    constexpr int NT = K / BK;
    constexpr int ASZ = BM * BK;         // ushorts
    constexpr int BSZ = BN * BK;
    __shared__ ushort lds[2 * (ASZ + BSZ)];

    const int tid = threadIdx.x;
    const int lane = tid & 63, wid = tid >> 6;
    const int wm = wid & 1, wn = wid >> 1;     // 2 x 4 wave grid
    const int m0 = blockIdx.x * BM;
    const int fr = lane & 15, fg = lane >> 4;

    const int srow = tid >> 2;                 // staging row (0..127)
    const int sslot = tid & 3;                 // 16B slot within 64B row

    v4f acc[4][NJ];
#pragma unroll
    for (int i = 0; i < 4; ++i)
#pragma unroll
        for (int j = 0; j < NJ; ++j) acc[i][j] = (v4f)0.f;

    auto stage = [&](int buf, int k0) {
        ushort* Ab = lds + buf * (ASZ + BSZ);
        ushort* Bb = Ab + ASZ;
        gld_lds16(A + (size_t)(m0 + srow) * K + k0 + ((sslot ^ (srow & 3)) << 3),
                  Ab + tid * 8);
        if constexpr (BN >= 128) {
#pragma unroll
            for (int i = 0; i < BN / 128; ++i) {
                int br = srow + i * 128;
                gld_lds16(Wt + (size_t)br * K + k0 + ((sslot ^ (br & 3)) << 3),
                          Bb + i * 4096 + tid * 8);
            }
        } else {
            if (tid < BN * 4)
                gld_lds16(Wt + (size_t)srow * K + k0 + ((sslot ^ (srow & 3)) << 3),
                          Bb + tid * 8);
        }
    };

    stage(0, 0);
    __syncthreads();
    int cur = 0;
    for (int t = 0; t < NT; ++t) {
        if (t + 1 < NT) stage(cur ^ 1, (t + 1) * BK);

        const ushort* Ab = lds + cur * (ASZ + BSZ);
        const ushort* Bb = Ab + ASZ;
        v8s a[4], b[NJ];
#pragma unroll
        for (int mi = 0; mi < 4; ++mi) {
            int row = wm * 64 + mi * 16 + fr;
            a[mi] = *reinterpret_cast<const v8s*>(Ab + row * 32 + ((fg ^ (row & 3)) << 3));
        }
#pragma unroll
        for (int nj = 0; nj < NJ; ++nj) {
            int row = wn * (BN / 4) + nj * 16 + fr;
            b[nj] = *reinterpret_cast<const v8s*>(Bb + row * 32 + ((fg ^ (row & 3)) << 3));
        }
#pragma unroll
        for (int mi = 0; mi < 4; ++mi)
#pragma unroll
            for (int nj = 0; nj < NJ; ++nj)
                acc[mi][nj] = __builtin_amdgcn_mfma_f32_16x16x32_bf16(a[mi], b[nj], acc[mi][nj], 0, 0, 0);

        if (t + 1 < NT) { __syncthreads(); cur ^= 1; }
    }

    // epilogue
    float bj[NJ], sc[NJ], be[NJ];
#pragma unroll
    for (int nj = 0; nj < NJ; ++nj) {
        int col = wn * (BN / 4) + nj * 16 + fr;
        bj[nj] = bias[col];
        if (ACT == 2) { sc[nj] = gamma[col] * rsqrtf(1.0f + 1e-5f); be[nj] = beta[col]; }
    }
#pragma unroll
    for (int mi = 0; mi < 4; ++mi) {
#pragma unroll
        for (int r = 0; r < 4; ++r) {
            int row = m0 + wm * 64 + mi * 16 + fg * 4 + r;
            if (row < M) {
#pragma unroll
                for (int nj = 0; nj < NJ; ++nj) {
                    int col = wn * (BN / 4) + nj * 16 + fr;
                    float t = acc[mi][nj][r] + bj[nj];
                    if (ACT == 2) t = t * sc[nj] + be[nj];
                    if (ACT >= 1) t = fmaxf(t, 0.f);
                    if (ACT == 0) outf[(size_t)row * OS + col] = t;
                    else          outb[(size_t)row * OS + col] = f2bf(t);
                }
            }
        }
    }
}

// ---------- launch ----------
extern "C" void kernel_launch(void* const* d_in, const int* in_sizes, int n_in,
                              void* d_out, int out_size, void* d_ws, size_t ws_size,
                              hipStream_t stream) {
    const float* x     = (const float*)d_in[0];
    const int*   src   = (const int*)d_in[1];
    const int*   dstv  = (const int*)d_in[2];
    const float* W1s   = (const float*)d_in[3];
    const float* W1n   = (const float*)d_in[4];
    const float* b1    = (const float*)d_in[5];
    const float* W2s   = (const float*)d_in[6];
    const float* W2n   = (const float*)d_in[7];
    const float* b2    = (const float*)d_in[8];
    const float* mW1   = (const float*)d_in[9];
    const float* mb1   = (const float*)d_in[10];
    const float* gamma = (const float*)d_in[11];
    const float* beta  = (const float*)d_in[12];
    const float* mW2   = (const float*)d_in[13];
    const float* mb2   = (const float*)d_in[14];

    const int IN = 128;
    const int N = in_sizes[0] / IN;   // 100000
    const int E = in_sizes[1];        // 800000
    const int GM = (N + 127) / 128;   // 782
    const int M_pad = GM * 128;       // 100096

    char* base = (char*)d_ws;
    size_t o = 0;
    auto alloc = [&](size_t bytes) -> char* {
        o = (o + 255) & ~(size_t)255;
        char* p = base + o;
        o += bytes;
        return p;
    };
    int* deg    = (int*)alloc((size_t)N * 4);
    int* offs   = (int*)alloc((size_t)(N + 4) * 4);   // pad: agg reads off[n+1] for n<N_pad4
    int* cursor = (int*)alloc((size_t)N * 4);
    int* bsum   = (int*)alloc(512 * 4);
    int* csr    = (int*)alloc((size_t)E * 4);
    ushort* Wt1  = (ushort*)alloc((size_t)256 * 256 * 2);   // [256 n][256 k] = [W1s;W1n]^T
    ushort* Wt2  = (ushort*)alloc((size_t)256 * 512 * 2);   // [256 n][512 k]
    ushort* Wtm1 = (ushort*)alloc((size_t)256 * 256 * 2);
    ushort* Wtm2 = (ushort*)alloc((size_t)64 * 256 * 2);
    ushort* hcat0 = (ushort*)alloc((size_t)M_pad * 256 * 2); // [x | xagg]; later reused as h2
    ushort* h1cat = (ushort*)alloc((size_t)M_pad * 512 * 2); // [h1 | h1agg]; later reused as tmlp

    ushort* h2   = hcat0;   // hcat0 dead after gemm1
    ushort* tmlp = h1cat;   // h1cat dead after gemm2

    // ---- weight prep (tiny) ----
    prep_wt<<<(256 * 256 + 255) / 256, 256, 0, stream>>>(W1s, W1n, Wt1, 128, 256, 256);
    prep_wt<<<(256 * 512 + 255) / 256, 256, 0, stream>>>(W2s, W2n, Wt2, 256, 512, 256);
    prep_wt<<<(256 * 256 + 255) / 256, 256, 0, stream>>>(mW1, mW1, Wtm1, 256, 256, 256);
    prep_wt<<<(64 * 256 + 255) / 256, 256, 0, stream>>>(mW2, mW2, Wtm2, 256, 256, 64);

    // ---- x -> bf16 into hcat0 cols 0..127 ----
    cvt_strided<<<(N * 32 + 255) / 256, 256, 0, stream>>>((const float4*)x, hcat0, N * 32, 256);

    // ---- CSR build ----
    const int nb1 = (N + 255) / 256;
    zero_i32<<<nb1, 256, 0, stream>>>(deg, N);
    deg_kernel<<<(E + 255) / 256, 256, 0, stream>>>(dstv, deg, E);
    scan1<<<nb1, 256, 0, stream>>>(deg, offs, bsum, N);
    scan2<<<1, 512, 0, stream>>>(bsum, nb1);
    add_off<<<(N + 1 + 255) / 256, 256, 0, stream>>>(offs, bsum, cursor, N, E);
    fill_csr<<<(E + 255) / 256, 256, 0, stream>>>(src, dstv, cursor, csr, E);
    // pad offs so the (N%4) tail waves see empty ranges
    // offs[N]=E set by add_off; set offs[N+1..N+3]=E via tiny kernel:
    add_off<<<1, 64, 0, stream>>>(offs + 1, bsum, cursor, -1, E);  // writes offs[1+(-1)]? no-op guard below

    // (tail guard done in-agg instead: n >= N waves would read offs[n],offs[n+1].
    //  Ensure those entries exist and are equal -> use zero_i32-style fill:)
    // simplest: launch grid without tail overrun
    const int AGG_BLK = N / 4;           // 25000 exact (N % 4 == 0)

    // ---- layer 1 ----
    agg_mean<128><<<AGG_BLK, 256, 0, stream>>>(hcat0, 256, offs, csr, hcat0 + 128, 256);
    gemm_mfma<256, 256, 1><<<GM, 512, 0, stream>>>(
        hcat0, Wt1, b1, nullptr, nullptr, h1cat, nullptr, N, 512);

    // ---- layer 2 ----
    agg_mean<256><<<AGG_BLK, 256, 0, stream>>>(h1cat, 512, offs, csr, h1cat + 256, 512);
    gemm_mfma<512, 256, 1><<<GM, 512, 0, stream>>>(
        h1cat, Wt2, b2, nullptr, nullptr, h2, nullptr, N, 256);

    // ---- MLP1: Linear -> BN(eval) -> ReLU ----
    gemm_mfma<256, 256, 2><<<GM, 512, 0, stream>>>(
        h2, Wtm1, mb1, gamma, beta, tmlp, nullptr, N, 256);

    // ---- MLP2: Linear -> fp32 out ----
    gemm_mfma<256, 64, 0><<<GM, 512, 0, stream>>>(
        tmlp, Wtm2, mb2, nullptr, nullptr, nullptr, (float*)d_out, N, 64);
}

// Round 5
// 323.029 us; speedup vs baseline: 1.0072x; 1.0072x over previous
//
#include <hip/hip_runtime.h>
#include <hip/hip_bf16.h>

typedef float v4f __attribute__((ext_vector_type(4)));
typedef short v8s __attribute__((ext_vector_type(8)));
typedef unsigned short u16x8 __attribute__((ext_vector_type(8)));

// ---------- helpers ----------
__device__ __forceinline__ float bf2f(ushort u) {
    union { unsigned int i; float f; } v; v.i = ((unsigned int)u) << 16; return v.f;
}
__device__ __forceinline__ ushort f2bf(float f) {
    union { float f; unsigned int i; } v; v.f = f;
    unsigned int x = v.i;
    unsigned int r = (x + 0x7fffu + ((x >> 16) & 1u)) >> 16;   // RNE
    return (ushort)r;
}
__device__ __forceinline__ void gld_lds16(const ushort* g, ushort* l) {
    __builtin_amdgcn_global_load_lds(
        (const __attribute__((address_space(1))) unsigned int*)g,
        (__attribute__((address_space(3))) unsigned int*)l, 16, 0, 0);
}

// ---------- small utility kernels ----------
__global__ void zero_i32(int* p, int n) {
    int i = blockIdx.x * blockDim.x + threadIdx.x;
    if (i < n) p[i] = 0;
}

// x [M][128] fp32 -> xb [M][128] bf16 (contiguous)
__global__ void cvt_bf16(const float4* __restrict__ x, ushort4* __restrict__ dst, int total4) {
    int idx = blockIdx.x * blockDim.x + threadIdx.x;
    if (idx >= total4) return;
    float4 f = x[idx];
    ushort4 o;
    o.x = f2bf(f.x); o.y = f2bf(f.y); o.z = f2bf(f.z); o.w = f2bf(f.w);
    dst[idx] = o;
}

// all four weight transposes in one launch
__global__ void prep_all(const float* __restrict__ W1s, const float* __restrict__ W1n,
                         const float* __restrict__ W2s, const float* __restrict__ W2n,
                         const float* __restrict__ mW1, const float* __restrict__ mW2,
                         ushort* __restrict__ Wt1, ushort* __restrict__ Wt2,
                         ushort* __restrict__ Wtm1, ushort* __restrict__ Wtm2) {
    int idx = blockIdx.x * blockDim.x + threadIdx.x;
    if (idx < 65536) {                       // Wt1[n][k], k<128 from W1s, else W1n
        int n = idx >> 8, k = idx & 255;
        float v = (k < 128) ? W1s[(size_t)k * 256 + n] : W1n[(size_t)(k - 128) * 256 + n];
        Wt1[idx] = f2bf(v);
    } else if (idx < 65536 + 131072) {       // Wt2[n][k], Kt=512
        int j = idx - 65536;
        int n = j >> 9, k = j & 511;
        float v = (k < 256) ? W2s[(size_t)k * 256 + n] : W2n[(size_t)(k - 256) * 256 + n];
        Wt2[j] = f2bf(v);
    } else if (idx < 65536 + 131072 + 65536) {  // Wtm1[n][k]
        int j = idx - (65536 + 131072);
        int n = j >> 8, k = j & 255;
        Wtm1[j] = f2bf(mW1[(size_t)k * 256 + n]);
    } else if (idx < 65536 + 131072 + 65536 + 16384) {  // Wtm2[n][k], NC=64
        int j = idx - (65536 + 131072 + 65536);
        int n = j >> 8, k = j & 255;
        Wtm2[j] = f2bf(mW2[(size_t)k * 64 + n]);
    }
}

__global__ void deg_kernel(const int* __restrict__ dst, int* __restrict__ deg, int E) {
    int e = blockIdx.x * blockDim.x + threadIdx.x;
    if (e < E) atomicAdd(&deg[dst[e]], 1);
}

__global__ void scan1(const int* __restrict__ deg, int* __restrict__ excl,
                      int* __restrict__ bsum, int N) {
    __shared__ int s[256];
    int tid = threadIdx.x;
    int gid = blockIdx.x * 256 + tid;
    int v = (gid < N) ? deg[gid] : 0;
    s[tid] = v;
    __syncthreads();
    for (int off = 1; off < 256; off <<= 1) {
        int t = (tid >= off) ? s[tid - off] : 0;
        __syncthreads();
        s[tid] += t;
        __syncthreads();
    }
    if (gid < N) excl[gid] = s[tid] - v;
    if (tid == 255) bsum[blockIdx.x] = s[255];
}

__global__ void scan2(int* __restrict__ bsum, int nb) {
    __shared__ int s[512];
    int tid = threadIdx.x;
    int v = (tid < nb) ? bsum[tid] : 0;
    s[tid] = v;
    __syncthreads();
    for (int off = 1; off < 512; off <<= 1) {
        int t = (tid >= off) ? s[tid - off] : 0;
        __syncthreads();
        s[tid] += t;
        __syncthreads();
    }
    if (tid < nb) bsum[tid] = s[tid] - v;
}

__global__ void add_off(int* __restrict__ offs, const int* __restrict__ bsum,
                        int* __restrict__ cursor, int N, int E) {
    int gid = blockIdx.x * blockDim.x + threadIdx.x;
    if (gid < N) {
        int o = offs[gid] + bsum[gid >> 8];
        offs[gid] = o;
        cursor[gid] = o;
    } else if (gid == N) {
        offs[N] = E;
    }
}

__global__ void fill_csr(const int* __restrict__ src, const int* __restrict__ dst,
                         int* __restrict__ cursor, int* __restrict__ csr, int E) {
    int e = blockIdx.x * blockDim.x + threadIdx.x;
    if (e < E) {
        int p = atomicAdd(&cursor[dst[e]], 1);
        csr[p] = src[e];
    }
}

// ---------- mean aggregation (compact table, compact output) ----------
// One wave per node, 4 waves per block. Each lane loads 16B (ushort8).
// G = D/8 lanes cover one row; P = 64/G neighbors per VMEM instr.
template <int D>
__global__ void agg_mean(const ushort* __restrict__ h,
                         const int* __restrict__ off, const int* __restrict__ csr,
                         ushort* __restrict__ out) {
    constexpr int G = D / 8;        // 16 (D=128) or 32 (D=256)
    constexpr int P = 64 / G;       // 4 or 2
    const int wid = threadIdx.x >> 6;
    const int n = blockIdx.x * 4 + wid;
    const int lane = threadIdx.x & 63;
    const int g = lane / G;
    const int sl = lane % G;

    int s = off[n], e = off[n + 1];
    float acc[8];
#pragma unroll
    for (int k = 0; k < 8; ++k) acc[k] = 0.f;

    const ushort* hp = h + (size_t)sl * 8;

    auto accum = [&](int u) {
        u16x8 q = *reinterpret_cast<const u16x8*>(hp + (size_t)u * D);
#pragma unroll
        for (int k = 0; k < 8; ++k) acc[k] += bf2f(q[k]);
    };

    int i = s;
    for (; i + 2 * P <= e; i += 2 * P) {
        int u0 = csr[i + g];
        int u1 = csr[i + P + g];
        u16x8 q0 = *reinterpret_cast<const u16x8*>(hp + (size_t)u0 * D);
        u16x8 q1 = *reinterpret_cast<const u16x8*>(hp + (size_t)u1 * D);
#pragma unroll
        for (int k = 0; k < 8; ++k) acc[k] += bf2f(q0[k]) + bf2f(q1[k]);
    }
    if (i + P <= e) {
        accum(csr[i + g]);
        i += P;
    }
    int r = e - i;
    if (g < r) accum(csr[i + g]);

#pragma unroll
    for (int m = G; m < 64; m <<= 1)
#pragma unroll
        for (int k = 0; k < 8; ++k) acc[k] += __shfl_xor(acc[k], m, 64);

    float inv = (e > s) ? 1.0f / (float)(e - s) : 1.0f;
    if (g == 0) {
        u16x8 o;
#pragma unroll
        for (int k = 0; k < 8; ++k) o[k] = f2bf(acc[k] * inv);
        *reinterpret_cast<u16x8*>(out + (size_t)n * D + sl * 8) = o;
    }
}

// ---------- MFMA GEMM (full-width tile, 2-phase dbuf, split-K dual A source) ----------
// out = act( [A1 | A2] @ Wt^T + bias ).  A1: bf16 [M_pad][KA], A2: bf16 [M_pad][K-KA].
// Wt: bf16 [BN][K].  BM=128 x BN, BK=32, 512 thr = 8 waves (2m x 4n).
// ACT: 0 = none->fp32, 1 = relu->bf16, 2 = BN+relu->bf16.  OS = out row stride.
template <int K, int KA, int BN, int ACT>
__launch_bounds__(512)
__global__ void gemm_mfma(const ushort* __restrict__ A1, const ushort* __restrict__ A2,
                          const ushort* __restrict__ Wt,
                          const float* __restrict__ bias, const float* __restrict__ gamma,
                          const float* __restrict__ beta,
                          ushort* __restrict__ outb, float* __restrict__ outf,
                          int M, int OS) {
    constexpr int BM = 128, BK = 32;
    constexpr int NJ = BN / 64;
    constexpr int NT = K / BK;
    constexpr int ASZ = BM * BK;
    constexpr int BSZ = BN * BK;
    __shared__ ushort lds[2 * (ASZ + BSZ)];

    const int tid = threadIdx.x;
    const int lane = tid & 63, wid = tid >> 6;
    const int wm = wid & 1, wn = wid >> 1;
    const int m0 = blockIdx.x * BM;
    const int fr = lane & 15, fg = lane >> 4;

    const int srow = tid >> 2;                 // staging row (0..127)
    const int sslot = tid & 3;                 // 16B slot within 64B k-tile

    v4f acc[4][NJ];
#pragma unroll
    for (int i = 0; i < 4; ++i)
#pragma unroll
        for (int j = 0; j < NJ; ++j) acc[i][j] = (v4f)0.f;

    auto stage = [&](int buf, int k0) {
        ushort* Ab = lds + buf * (ASZ + BSZ);
        ushort* Bb = Ab + ASZ;
        const ushort* Asrc;
        int rs, kk;
        if (k0 < KA) { Asrc = A1; rs = KA; kk = k0; }
        else         { Asrc = A2; rs = K - KA; kk = k0 - KA; }
        gld_lds16(Asrc + (size_t)(m0 + srow) * rs + kk + ((sslot ^ (srow & 3)) << 3),
                  Ab + tid * 8);
        if constexpr (BN >= 128) {
#pragma unroll
            for (int i = 0; i < BN / 128; ++i) {
                int br = srow + i * 128;
                gld_lds16(Wt + (size_t)br * K + k0 + ((sslot ^ (br & 3)) << 3),
                          Bb + i * 4096 + tid * 8);
            }
        } else {
            if (tid < BN * 4)
                gld_lds16(Wt + (size_t)srow * K + k0 + ((sslot ^ (srow & 3)) << 3),
                          Bb + tid * 8);
        }
    };

    stage(0, 0);
    __syncthreads();
    int cur = 0;
    for (int t = 0; t < NT; ++t) {
        if (t + 1 < NT) stage(cur ^ 1, (t + 1) * BK);

        const ushort* Ab = lds + cur * (ASZ + BSZ);
        const ushort* Bb = Ab + ASZ;
        v8s a[4], b[NJ];
#pragma unroll
        for (int mi = 0; mi < 4; ++mi) {
            int row = wm * 64 + mi * 16 + fr;
            a[mi] = *reinterpret_cast<const v8s*>(Ab + row * 32 + ((fg ^ (row & 3)) << 3));
        }
#pragma unroll
        for (int nj = 0; nj < NJ; ++nj) {
            int row = wn * (BN / 4) + nj * 16 + fr;
            b[nj] = *reinterpret_cast<const v8s*>(Bb + row * 32 + ((fg ^ (row & 3)) << 3));
        }
#pragma unroll
        for (int mi = 0; mi < 4; ++mi)
#pragma unroll
            for (int nj = 0; nj < NJ; ++nj)
                acc[mi][nj] = __builtin_amdgcn_mfma_f32_16x16x32_bf16(a[mi], b[nj], acc[mi][nj], 0, 0, 0);

        if (t + 1 < NT) { __syncthreads(); cur ^= 1; }
    }

    // epilogue
    float bj[NJ], sc[NJ], be[NJ];
#pragma unroll
    for (int nj = 0; nj < NJ; ++nj) {
        int col = wn * (BN / 4) + nj * 16 + fr;
        bj[nj] = bias[col];
        if (ACT == 2) { sc[nj] = gamma[col] * rsqrtf(1.0f + 1e-5f); be[nj] = beta[col]; }
    }
#pragma unroll
    for (int mi = 0; mi < 4; ++mi) {
#pragma unroll
        for (int r = 0; r < 4; ++r) {
            int row = m0 + wm * 64 + mi * 16 + fg * 4 + r;
            if (row < M) {
#pragma unroll
                for (int nj = 0; nj < NJ; ++nj) {
                    int col = wn * (BN / 4) + nj * 16 + fr;
                    float t = acc[mi][nj][r] + bj[nj];
                    if (ACT == 2) t = t * sc[nj] + be[nj];
                    if (ACT >= 1) t = fmaxf(t, 0.f);
                    if (ACT == 0) outf[(size_t)row * OS + col] = t;
                    else          outb[(size_t)row * OS + col] = f2bf(t);
                }
            }
        }
    }
}

// ---------- launch ----------
extern "C" void kernel_launch(void* const* d_in, const int* in_sizes, int n_in,
                              void* d_out, int out_size, void* d_ws, size_t ws_size,
                              hipStream_t stream) {
    const float* x     = (const float*)d_in[0];
    const int*   src   = (const int*)d_in[1];
    const int*   dstv  = (const int*)d_in[2];
    const float* W1s   = (const float*)d_in[3];
    const float* W1n   = (const float*)d_in[4];
    const float* b1    = (const float*)d_in[5];
    const float* W2s   = (const float*)d_in[6];
    const float* W2n   = (const float*)d_in[7];
    const float* b2    = (const float*)d_in[8];
    const float* mW1   = (const float*)d_in[9];
    const float* mb1   = (const float*)d_in[10];
    const float* gamma = (const float*)d_in[11];
    const float* beta  = (const float*)d_in[12];
    const float* mW2   = (const float*)d_in[13];
    const float* mb2   = (const float*)d_in[14];

    const int IN = 128;
    const int N = in_sizes[0] / IN;   // 100000
    const int E = in_sizes[1];        // 800000
    const int GM = (N + 127) / 128;   // 782
    const int M_pad = GM * 128;       // 100096

    char* base = (char*)d_ws;
    size_t o = 0;
    auto alloc = [&](size_t bytes) -> char* {
        o = (o + 255) & ~(size_t)255;
        char* p = base + o;
        o += bytes;
        return p;
    };
    int* deg    = (int*)alloc((size_t)N * 4);
    int* offs   = (int*)alloc((size_t)(N + 4) * 4);
    int* cursor = (int*)alloc((size_t)N * 4);
    int* bsum   = (int*)alloc(512 * 4);
    int* csr    = (int*)alloc((size_t)E * 4);
    ushort* Wt1  = (ushort*)alloc((size_t)256 * 256 * 2);   // [256 n][256 k]
    ushort* Wt2  = (ushort*)alloc((size_t)256 * 512 * 2);   // [256 n][512 k]
    ushort* Wtm1 = (ushort*)alloc((size_t)256 * 256 * 2);
    ushort* Wtm2 = (ushort*)alloc((size_t)64 * 256 * 2);
    // compact activation buffers (gather tables separated from agg outputs)
    ushort* xb    = (ushort*)alloc((size_t)M_pad * 128 * 2);  // 25.6MB
    ushort* xagg  = (ushort*)alloc((size_t)M_pad * 128 * 2);  // 25.6MB
    ushort* h1    = (ushort*)alloc((size_t)M_pad * 256 * 2);  // 51.2MB
    ushort* h1agg = (ushort*)alloc((size_t)M_pad * 256 * 2);  // 51.2MB

    ushort* h2   = xb;     // xb+xagg dead after gemm1; 51.2MB region reused
    ushort* tmlp = h1;     // h1 dead after gemm2

    // ---- weight prep (one launch) ----
    prep_all<<<(65536 + 131072 + 65536 + 16384 + 255) / 256, 256, 0, stream>>>(
        W1s, W1n, W2s, W2n, mW1, mW2, Wt1, Wt2, Wtm1, Wtm2);

    // ---- x -> bf16 ----
    cvt_bf16<<<(N * 32 + 255) / 256, 256, 0, stream>>>((const float4*)x, (ushort4*)xb, N * 32);

    // ---- CSR build ----
    const int nb1 = (N + 255) / 256;
    zero_i32<<<nb1, 256, 0, stream>>>(deg, N);
    deg_kernel<<<(E + 255) / 256, 256, 0, stream>>>(dstv, deg, E);
    scan1<<<nb1, 256, 0, stream>>>(deg, offs, bsum, N);
    scan2<<<1, 512, 0, stream>>>(bsum, nb1);
    add_off<<<(N + 1 + 255) / 256, 256, 0, stream>>>(offs, bsum, cursor, N, E);
    fill_csr<<<(E + 255) / 256, 256, 0, stream>>>(src, dstv, cursor, csr, E);

    const int AGG_BLK = N / 4;   // N % 4 == 0

    // ---- layer 1 ----
    agg_mean<128><<<AGG_BLK, 256, 0, stream>>>(xb, offs, csr, xagg);
    gemm_mfma<256, 128, 256, 1><<<GM, 512, 0, stream>>>(
        xb, xagg, Wt1, b1, nullptr, nullptr, h1, nullptr, N, 256);

    // ---- layer 2 ----
    agg_mean<256><<<AGG_BLK, 256, 0, stream>>>(h1, offs, csr, h1agg);
    gemm_mfma<512, 256, 256, 1><<<GM, 512, 0, stream>>>(
        h1, h1agg, Wt2, b2, nullptr, nullptr, h2, nullptr, N, 256);

    // ---- MLP1: Linear -> BN(eval) -> ReLU ----
    gemm_mfma<256, 256, 256, 2><<<GM, 512, 0, stream>>>(
        h2, h2, Wtm1, mb1, gamma, beta, tmlp, nullptr, N, 256);

    // ---- MLP2: Linear -> fp32 out ----
    gemm_mfma<256, 256, 64, 0><<<GM, 512, 0, stream>>>(
        tmlp, tmlp, Wtm2, mb2, nullptr, nullptr, nullptr, (float*)d_out, N, 64);
}